// Round 8
// baseline (52.617 us; speedup 1.0000x reference)
//
#include <hip/hip_runtime.h>

#define BLK 256
#define NBLOCKS 2048

typedef float floatx4 __attribute__((ext_vector_type(4)));

__inline__ __device__ float waveReduceSumF(float v) {
    #pragma unroll
    for (int o = 32; o > 0; o >>= 1) v += __shfl_down(v, o, 64);
    return v;
}
__inline__ __device__ unsigned int waveReduceSumU(unsigned int v) {
    #pragma unroll
    for (int o = 32; o > 0; o >>= 1) v += __shfl_down(v, o, 64);
    return v;
}

// Streaming kernel, split-cache policy:
//   W1 loaded PLAIN (cacheable; 128 MB < 256 MB LLC -> stays L3-resident
//   across graph replays),
//   W2 loaded NT (evict-first; streams HBM without displacing W1).
// Interleaved so the LLC-hit stream and the HBM stream overlap.
// Counts ALL nonzeros (no bounds checks); <=2-element tail corrected in final.
__global__ __launch_bounds__(BLK) void frac_split_kernel(
    const float* __restrict__ x1, long long nvec1,
    const float* __restrict__ x2, long long nvec2,
    float* __restrict__ psum1, unsigned int* __restrict__ pcnt1,
    float* __restrict__ psum2, unsigned int* __restrict__ pcnt2)
{
    const long long stride = (long long)gridDim.x * blockDim.x;
    const long long tid0   = (long long)blockIdx.x * blockDim.x + threadIdx.x;
    const floatx4* __restrict__ xv1 = (const floatx4*)x1;
    const floatx4* __restrict__ xv2 = (const floatx4*)x2;

    float s1 = 0.f, s2 = 0.f;
    unsigned int c1 = 0u, c2 = 0u;

    const long long nmin = (nvec1 < nvec2) ? nvec1 : nvec2;
    long long i = tid0;
    for (; i < nmin; i += stride) {
        floatx4 a = xv1[i];                                // plain: LLC-resident
        floatx4 b = __builtin_nontemporal_load(&xv2[i]);   // nt: HBM stream
        float a0 = fabsf(a.x), a1 = fabsf(a.y), a2 = fabsf(a.z), a3 = fabsf(a.w);
        float b0 = fabsf(b.x), b1 = fabsf(b.y), b2 = fabsf(b.z), b3 = fabsf(b.w);
        s1 += (a0 + a1) + (a2 + a3);
        s2 += (b0 + b1) + (b2 + b3);
        c1 += (unsigned int)(a0 > 0.f) + (unsigned int)(a1 > 0.f)
            + (unsigned int)(a2 > 0.f) + (unsigned int)(a3 > 0.f);
        c2 += (unsigned int)(b0 > 0.f) + (unsigned int)(b1 > 0.f)
            + (unsigned int)(b2 > 0.f) + (unsigned int)(b3 > 0.f);
    }
    const long long irem = i;
    for (; i < nvec1; i += stride) {
        floatx4 a = xv1[i];
        float a0 = fabsf(a.x), a1 = fabsf(a.y), a2 = fabsf(a.z), a3 = fabsf(a.w);
        s1 += (a0 + a1) + (a2 + a3);
        c1 += (unsigned int)(a0 > 0.f) + (unsigned int)(a1 > 0.f)
            + (unsigned int)(a2 > 0.f) + (unsigned int)(a3 > 0.f);
    }
    for (i = irem; i < nvec2; i += stride) {
        floatx4 b = __builtin_nontemporal_load(&xv2[i]);
        float b0 = fabsf(b.x), b1 = fabsf(b.y), b2 = fabsf(b.z), b3 = fabsf(b.w);
        s2 += (b0 + b1) + (b2 + b3);
        c2 += (unsigned int)(b0 > 0.f) + (unsigned int)(b1 > 0.f)
            + (unsigned int)(b2 > 0.f) + (unsigned int)(b3 > 0.f);
    }

    // wave reduce then cross-wave via LDS (BLK=256 -> 4 waves)
    s1 = waveReduceSumF(s1); s2 = waveReduceSumF(s2);
    c1 = waveReduceSumU(c1); c2 = waveReduceSumU(c2);
    __shared__ float ls1[BLK / 64], ls2[BLK / 64];
    __shared__ unsigned int lc1[BLK / 64], lc2[BLK / 64];
    int lane = threadIdx.x & 63;
    int wid  = threadIdx.x >> 6;
    if (lane == 0) { ls1[wid] = s1; ls2[wid] = s2; lc1[wid] = c1; lc2[wid] = c2; }
    __syncthreads();
    if (wid == 0) {
        float fs1 = (lane < BLK / 64) ? ls1[lane] : 0.f;
        float fs2 = (lane < BLK / 64) ? ls2[lane] : 0.f;
        unsigned int fc1 = (lane < BLK / 64) ? lc1[lane] : 0u;
        unsigned int fc2 = (lane < BLK / 64) ? lc2[lane] : 0u;
        fs1 = waveReduceSumF(fs1); fs2 = waveReduceSumF(fs2);
        fc1 = waveReduceSumU(fc1); fc2 = waveReduceSumU(fc2);
        if (lane == 0) {
            psum1[blockIdx.x] = fs1; pcnt1[blockIdx.x] = fc1;
            psum2[blockIdx.x] = fs2; pcnt2[blockIdx.x] = fc2;
        }
    }
}

// Single-block final reduction + tail corrections + scalar epilogue.
__global__ __launch_bounds__(BLK) void frac_final_kernel(
    const float* __restrict__ psum1, const unsigned int* __restrict__ pcnt1,
    const float* __restrict__ psum2, const unsigned int* __restrict__ pcnt2,
    int nblocks,
    const float* __restrict__ x1, long long n1, long long nc1,
    const float* __restrict__ x2, long long n2, long long nc2,
    const float* __restrict__ lambda_p,
    const int* __restrict__ epoch_p,
    const int* __restrict__ total_p,
    float* __restrict__ out)
{
    float s1 = 0.f, s2 = 0.f;
    unsigned int c1 = 0u, c2 = 0u;
    for (int i = threadIdx.x; i < nblocks; i += blockDim.x) {
        s1 += psum1[i]; c1 += pcnt1[i];
        s2 += psum2[i]; c2 += pcnt2[i];
    }
    s1 = waveReduceSumF(s1); s2 = waveReduceSumF(s2);
    c1 = waveReduceSumU(c1); c2 = waveReduceSumU(c2);
    __shared__ float ls1[BLK / 64], ls2[BLK / 64];
    __shared__ unsigned int lc1[BLK / 64], lc2[BLK / 64];
    int lane = threadIdx.x & 63;
    int wid  = threadIdx.x >> 6;
    if (lane == 0) { ls1[wid] = s1; ls2[wid] = s2; lc1[wid] = c1; lc2[wid] = c2; }
    __syncthreads();
    if (threadIdx.x == 0) {
        float S1 = 0.f, S2 = 0.f;
        long long C1 = 0, C2 = 0;
        #pragma unroll
        for (int w = 0; w < BLK / 64; ++w) {
            S1 += ls1[w]; S2 += ls2[w]; C1 += (long long)lc1[w]; C2 += (long long)lc2[w];
        }
        // Tail corrections:
        // (a) scalars in [4*(n/4), n) never streamed: add to sum (+count if < nc)
        // (b) elements in [nc, 4*(n/4)) were counted but are outside count range: subtract
        long long v4 = (n1 >> 2) << 2;
        for (long long j = v4; j < n1; ++j) {
            float a = fabsf(x1[j]);
            S1 += a;
            if (j < nc1 && a > 0.f) C1++;
        }
        for (long long j = nc1; j < v4; ++j)
            if (fabsf(x1[j]) > 0.f) C1--;
        long long w4 = (n2 >> 2) << 2;
        for (long long j = w4; j < n2; ++j) {
            float a = fabsf(x2[j]);
            S2 += a;
            if (j < nc2 && a > 0.f) C2++;
        }
        for (long long j = nc2; j < w4; ++j)
            if (fabsf(x2[j]) > 0.f) C2--;

        float lam = *lambda_p;
        float progress = 1.0f - (float)(*epoch_p) / (float)(*total_p);
        float adj_alpha = 0.1f  * progress;
        float adj_beta  = 0.01f * progress;

        // fractal_loss = ((0 + S1^2) * lam + S2^2) * lam
        float fractal = (S1 * S1) * lam;
        fractal = (fractal + S2 * S2) * lam;

        // multi-resolution: (C/nb)^2 per tensor, RESOLUTION_FACTOR = 2
        float m1 = (float)((double)C1 / (double)(nc1 / 3));
        float m2 = (float)((double)C2 / (double)(nc2 / 3));
        float mrl = m1 * m1 + m2 * m2;

        *out = adj_alpha * fractal + adj_beta * mrl;
    }
}

extern "C" void kernel_launch(void* const* d_in, const int* in_sizes, int n_in,
                              void* d_out, int out_size, void* d_ws, size_t ws_size,
                              hipStream_t stream) {
    const float* W1       = (const float*)d_in[0];
    const float* W2       = (const float*)d_in[1];
    const float* lambda_p = (const float*)d_in[2];
    const int*   epoch_p  = (const int*)d_in[3];
    const int*   total_p  = (const int*)d_in[4];
    float* out = (float*)d_out;

    long long n1 = (long long)in_sizes[0];
    long long n2 = (long long)in_sizes[1];
    long long nc1 = (n1 / 3) * 3, nc2 = (n2 / 3) * 3;

    // Workspace layout: [psum1 | psum2 | pcnt1 | pcnt2], NBLOCKS each.
    float* psum1 = (float*)d_ws;
    float* psum2 = psum1 + NBLOCKS;
    unsigned int* pcnt1 = (unsigned int*)(psum2 + NBLOCKS);
    unsigned int* pcnt2 = pcnt1 + NBLOCKS;

    frac_split_kernel<<<NBLOCKS, BLK, 0, stream>>>(
        W1, n1 >> 2, W2, n2 >> 2, psum1, pcnt1, psum2, pcnt2);
    frac_final_kernel<<<1, BLK, 0, stream>>>(
        psum1, pcnt1, psum2, pcnt2, NBLOCKS,
        W1, n1, nc1, W2, n2, nc2,
        lambda_p, epoch_p, total_p, out);
}

// Round 9
// 47.872 us; speedup vs baseline: 1.0991x; 1.0991x over previous
//
#include <hip/hip_runtime.h>

#define BLK 256
#define NBLOCKS 2048

typedef float floatx4 __attribute__((ext_vector_type(4)));

__inline__ __device__ float waveReduceSumF(float v) {
    #pragma unroll
    for (int o = 32; o > 0; o >>= 1) v += __shfl_down(v, o, 64);
    return v;
}
__inline__ __device__ unsigned int waveReduceSumU(unsigned int v) {
    #pragma unroll
    for (int o = 32; o > 0; o >>= 1) v += __shfl_down(v, o, 64);
    return v;
}

__device__ __forceinline__ void accum4(floatx4 v, float& s, unsigned int& c) {
    float a0 = fabsf(v.x), a1 = fabsf(v.y), a2 = fabsf(v.z), a3 = fabsf(v.w);
    s += (a0 + a1) + (a2 + a3);
    c += (unsigned int)(a0 > 0.f) + (unsigned int)(a1 > 0.f)
       + (unsigned int)(a2 > 0.f) + (unsigned int)(a3 > 0.f);
}

// Block-cyclic 4x-unrolled nt stream: per iteration each block covers a
// contiguous 16KB window (4 wave-coalesced 1KB loads in flight per thread,
// addresses BLK*16B apart -> same DRAM page neighborhood), then strides by
// grid*64KB. Counts ALL nonzeros; tail/range corrections in final kernel.
__device__ __forceinline__ void streamTensor(const floatx4* __restrict__ xv,
                                             long long nvec,
                                             float& s, unsigned int& c) {
    const long long perBlock = 4LL * BLK;
    const long long gstride  = perBlock * (long long)gridDim.x;
    long long base = (long long)blockIdx.x * perBlock + threadIdx.x;
    for (; base + 3LL * BLK < nvec; base += gstride) {
        floatx4 v0 = __builtin_nontemporal_load(&xv[base]);
        floatx4 v1 = __builtin_nontemporal_load(&xv[base + BLK]);
        floatx4 v2 = __builtin_nontemporal_load(&xv[base + 2 * BLK]);
        floatx4 v3 = __builtin_nontemporal_load(&xv[base + 3 * BLK]);
        accum4(v0, s, c);
        accum4(v1, s, c);
        accum4(v2, s, c);
        accum4(v3, s, c);
    }
    // Partial chunk (none for these shapes; generic correctness)
    for (; base < nvec; base += BLK) {
        floatx4 v = __builtin_nontemporal_load(&xv[base]);
        accum4(v, s, c);
    }
}

__global__ __launch_bounds__(BLK) void frac_stream_kernel(
    const float* __restrict__ x1, long long nvec1,
    const float* __restrict__ x2, long long nvec2,
    float* __restrict__ psum1, unsigned int* __restrict__ pcnt1,
    float* __restrict__ psum2, unsigned int* __restrict__ pcnt2)
{
    float s1 = 0.f, s2 = 0.f;
    unsigned int c1 = 0u, c2 = 0u;

    streamTensor((const floatx4*)x1, nvec1, s1, c1);
    streamTensor((const floatx4*)x2, nvec2, s2, c2);

    // wave reduce then cross-wave via LDS (BLK=256 -> 4 waves)
    s1 = waveReduceSumF(s1); s2 = waveReduceSumF(s2);
    c1 = waveReduceSumU(c1); c2 = waveReduceSumU(c2);
    __shared__ float ls1[BLK / 64], ls2[BLK / 64];
    __shared__ unsigned int lc1[BLK / 64], lc2[BLK / 64];
    int lane = threadIdx.x & 63;
    int wid  = threadIdx.x >> 6;
    if (lane == 0) { ls1[wid] = s1; ls2[wid] = s2; lc1[wid] = c1; lc2[wid] = c2; }
    __syncthreads();
    if (wid == 0) {
        float fs1 = (lane < BLK / 64) ? ls1[lane] : 0.f;
        float fs2 = (lane < BLK / 64) ? ls2[lane] : 0.f;
        unsigned int fc1 = (lane < BLK / 64) ? lc1[lane] : 0u;
        unsigned int fc2 = (lane < BLK / 64) ? lc2[lane] : 0u;
        fs1 = waveReduceSumF(fs1); fs2 = waveReduceSumF(fs2);
        fc1 = waveReduceSumU(fc1); fc2 = waveReduceSumU(fc2);
        if (lane == 0) {
            psum1[blockIdx.x] = fs1; pcnt1[blockIdx.x] = fc1;
            psum2[blockIdx.x] = fs2; pcnt2[blockIdx.x] = fc2;
        }
    }
}

// Single-block final reduction + tail corrections + scalar epilogue.
__global__ __launch_bounds__(BLK) void frac_final_kernel(
    const float* __restrict__ psum1, const unsigned int* __restrict__ pcnt1,
    const float* __restrict__ psum2, const unsigned int* __restrict__ pcnt2,
    int nblocks,
    const float* __restrict__ x1, long long n1, long long nc1,
    const float* __restrict__ x2, long long n2, long long nc2,
    const float* __restrict__ lambda_p,
    const int* __restrict__ epoch_p,
    const int* __restrict__ total_p,
    float* __restrict__ out)
{
    float s1 = 0.f, s2 = 0.f;
    unsigned int c1 = 0u, c2 = 0u;
    for (int i = threadIdx.x; i < nblocks; i += blockDim.x) {
        s1 += psum1[i]; c1 += pcnt1[i];
        s2 += psum2[i]; c2 += pcnt2[i];
    }
    s1 = waveReduceSumF(s1); s2 = waveReduceSumF(s2);
    c1 = waveReduceSumU(c1); c2 = waveReduceSumU(c2);
    __shared__ float ls1[BLK / 64], ls2[BLK / 64];
    __shared__ unsigned int lc1[BLK / 64], lc2[BLK / 64];
    int lane = threadIdx.x & 63;
    int wid  = threadIdx.x >> 6;
    if (lane == 0) { ls1[wid] = s1; ls2[wid] = s2; lc1[wid] = c1; lc2[wid] = c2; }
    __syncthreads();
    if (threadIdx.x == 0) {
        float S1 = 0.f, S2 = 0.f;
        long long C1 = 0, C2 = 0;
        #pragma unroll
        for (int w = 0; w < BLK / 64; ++w) {
            S1 += ls1[w]; S2 += ls2[w]; C1 += (long long)lc1[w]; C2 += (long long)lc2[w];
        }
        // Tail corrections:
        // (a) scalars in [4*(n/4), n) never streamed: add to sum (+count if < nc)
        // (b) elements in [nc, 4*(n/4)) were counted but are outside count range: subtract
        long long v4 = (n1 >> 2) << 2;
        for (long long j = v4; j < n1; ++j) {
            float a = fabsf(x1[j]);
            S1 += a;
            if (j < nc1 && a > 0.f) C1++;
        }
        for (long long j = nc1; j < v4; ++j)
            if (fabsf(x1[j]) > 0.f) C1--;
        long long w4 = (n2 >> 2) << 2;
        for (long long j = w4; j < n2; ++j) {
            float a = fabsf(x2[j]);
            S2 += a;
            if (j < nc2 && a > 0.f) C2++;
        }
        for (long long j = nc2; j < w4; ++j)
            if (fabsf(x2[j]) > 0.f) C2--;

        float lam = *lambda_p;
        float progress = 1.0f - (float)(*epoch_p) / (float)(*total_p);
        float adj_alpha = 0.1f  * progress;
        float adj_beta  = 0.01f * progress;

        // fractal_loss = ((0 + S1^2) * lam + S2^2) * lam
        float fractal = (S1 * S1) * lam;
        fractal = (fractal + S2 * S2) * lam;

        // multi-resolution: (C/nb)^2 per tensor, RESOLUTION_FACTOR = 2
        float m1 = (float)((double)C1 / (double)(nc1 / 3));
        float m2 = (float)((double)C2 / (double)(nc2 / 3));
        float mrl = m1 * m1 + m2 * m2;

        *out = adj_alpha * fractal + adj_beta * mrl;
    }
}

extern "C" void kernel_launch(void* const* d_in, const int* in_sizes, int n_in,
                              void* d_out, int out_size, void* d_ws, size_t ws_size,
                              hipStream_t stream) {
    const float* W1       = (const float*)d_in[0];
    const float* W2       = (const float*)d_in[1];
    const float* lambda_p = (const float*)d_in[2];
    const int*   epoch_p  = (const int*)d_in[3];
    const int*   total_p  = (const int*)d_in[4];
    float* out = (float*)d_out;

    long long n1 = (long long)in_sizes[0];
    long long n2 = (long long)in_sizes[1];
    long long nc1 = (n1 / 3) * 3, nc2 = (n2 / 3) * 3;

    // Workspace layout: [psum1 | psum2 | pcnt1 | pcnt2], NBLOCKS each.
    float* psum1 = (float*)d_ws;
    float* psum2 = psum1 + NBLOCKS;
    unsigned int* pcnt1 = (unsigned int*)(psum2 + NBLOCKS);
    unsigned int* pcnt2 = pcnt1 + NBLOCKS;

    frac_stream_kernel<<<NBLOCKS, BLK, 0, stream>>>(
        W1, n1 >> 2, W2, n2 >> 2, psum1, pcnt1, psum2, pcnt2);
    frac_final_kernel<<<1, BLK, 0, stream>>>(
        psum1, pcnt1, psum2, pcnt2, NBLOCKS,
        W1, n1, nc1, W2, n2, nc2,
        lambda_p, epoch_p, total_p, out);
}